// Round 3
// baseline (758.816 us; speedup 1.0000x reference)
//
#include <hip/hip_runtime.h>
#include <hip/hip_cooperative_groups.h>

namespace cg = cooperative_groups;

#define HW_S   65536      // 256*256 small image pixels
#define NFEAT  10
#define DIM    33
#define DIM2   1089       // 33^2
#define DIM3   35937      // 33^3
#define LUT_ELEMS (3*DIM3)
#define IMG_HW 8294400    // 2160*3840
#define IMG_ELEMS (3*IMG_HW)
#define NGROUPS (IMG_HW/4)

// ws layout (32-bit slots): [0]=amax bits, [1]=unused, [16..656)=partials (64x10),
// [4096..5086)=K

__device__ __forceinline__ float ub(unsigned int w, int b) {
    return (float)((w >> (8 * b)) & 0xffu);   // v_cvt_f32_ubyteN, 1 VALU
}

// Single cooperative kernel: 256 blocks x 1024 threads, 1 block/CU (LDS-capped).
__global__ __launch_bounds__(1024) void fused_all(
    const int* __restrict__ msb, const int* __restrict__ lsb,
    const float* __restrict__ fm, const float* __restrict__ fl,
    const float* __restrict__ lut_cat, const float* __restrict__ s_layers,
    const float* __restrict__ luts, const float* __restrict__ w_layers,
    const float* __restrict__ img,
    float* __restrict__ partial, float* __restrict__ Kg,
    unsigned int* __restrict__ amax,
    float* __restrict__ out_lut, float* __restrict__ out)
{
    extern __shared__ unsigned int qs[];      // 35937 dwords = 143748 B
    __shared__ float s4[16][NFEAT];
    __shared__ float chunk_s[80], pooled_s[NFEAT], w_s[NFEAT], R_s[150];
    __shared__ float K_s[3 * DIM * NFEAT];    // 990 floats
    __shared__ float smx[16];
    __shared__ float bmax_s;

    cg::grid_group grid = cg::this_grid();
    const int tid = threadIdx.x, bid = blockIdx.x;
    const int lane = tid & 63, wave = tid >> 6;

    // ---------------- Phase A: feature gather + pool (blocks 0..63) --------
    if (bid < 64) {
        int p = bid * 1024 + tid;             // covers all 65536 pixels
        int im = msb[p] * 4096 + msb[HW_S + p] * 256 + msb[2 * HW_S + p] * 16;
        int il = lsb[p] * 4096 + lsb[HW_S + p] * 256 + lsb[2 * HW_S + p] * 16;
        const float2* rm = (const float2*)(fm + im * NFEAT);  // 40B rows, 8B aligned
        const float2* rl = (const float2*)(fl + il * NFEAT);
        float acc[NFEAT];
#pragma unroll
        for (int h = 0; h < 5; ++h) {
            float2 a = rm[h], b = rl[h];
            acc[2 * h]     = a.x + b.x;
            acc[2 * h + 1] = a.y + b.y;
        }
#pragma unroll
        for (int f = 0; f < NFEAT; ++f) {
            float v = acc[f];
#pragma unroll
            for (int off = 32; off >= 1; off >>= 1) v += __shfl_down(v, off, 64);
            acc[f] = v;
        }
        if (lane == 0) {
#pragma unroll
            for (int f = 0; f < NFEAT; ++f) s4[wave][f] = acc[f];
        }
        __syncthreads();
        if (tid < NFEAT) {
            float s = 0.f;
#pragma unroll
            for (int w2 = 0; w2 < 16; ++w2) s += s4[w2][tid];
            partial[bid * NFEAT + tid] = s;
        }
    }
    __threadfence();
    grid.sync();
    __threadfence();

    // ---------------- Phase B: pooled -> weights -> R -> K (block 0) -------
    if (bid == 0) {
        if (tid < 80) {   // fixed-order tree: 8 chunks x 8 blocks, per feature
            int f = tid % 10, ch = tid / 10;
            float s = 0.f;
            for (int b = ch * 8; b < ch * 8 + 8; ++b) s += partial[b * NFEAT + f];
            chunk_s[tid] = s;
        }
        __syncthreads();
        if (tid < NFEAT) {
            float v = 0.f;
#pragma unroll
            for (int ch = 0; ch < 8; ++ch) v += chunk_s[ch * 10 + tid];
            v *= (1.0f / 65536.0f);
            v = rintf(v * 2.0f) * 0.5f;
            v = fminf(fmaxf(v, -16.0f), 15.5f);
            pooled_s[tid] = v;
        }
        __syncthreads();
        if (tid < NFEAT) {
            float wsum = 0.f;
            for (int i = 0; i < 5; ++i) {
                int m0 = (int)(pooled_s[2 * i] * 2.0f) + 32;
                int m1 = (int)(pooled_s[2 * i + 1] * 2.0f) + 32;
                wsum += (lut_cat[(i * 4096 + m0 * 64 + m1) * NFEAT + tid] - 32.0f) * 0.25f;
            }
            w_s[tid] = wsum;
        }
        __syncthreads();
        if (tid < 150) {  // R[s][c][w] = sum_n weights[n] * luts[s*30+n*3+c, w]
            int w = tid % 10, sc = tid / 10, c = sc % 3, s = sc / 3;
            float r = 0.f;
            for (int n = 0; n < NFEAT; ++n)
                r += w_s[n] * luts[(s * 30 + n * 3 + c) * NFEAT + w];
            R_s[tid] = r;
        }
        __syncthreads();
        if (tid < 3 * DIM * NFEAT) {   // K[c][a][w], 990 elems, one shot
            int w = tid % 10, a = (tid / 10) % DIM, c = tid / (10 * DIM);
            float k = 0.f;
#pragma unroll
            for (int s = 0; s < 5; ++s)
                k += s_layers[a * 5 + s] * R_s[(s * 3 + c) * 10 + w];
            Kg[tid] = k;
        }
    }
    __threadfence();
    grid.sync();
    __threadfence();

    // ------- Phase C: f32 d3lut output + global absmax (ALL 256 blocks) ----
    if (tid < 3 * DIM * NFEAT) K_s[tid] = Kg[tid];
    __syncthreads();
    {
        int e = bid * 1024 + tid;             // 107811 < 262144: <=1 elem/thread
        bool valid = e < LUT_ELEMS;
        float v = 0.f;
        if (valid) {
            int c = e / DIM3;
            int rem = e - c * DIM3;
            int i = rem / DIM2;
            int j = (rem / DIM) % DIM;
            int k = rem % DIM;
            int a, col;
            if (c == 0)      { a = k; col = i * DIM + j; }
            else if (c == 1) { a = j; col = i * DIM + k; }
            else             { a = i; col = j * DIM + k; }
            const float* Kr = K_s + (c * DIM + a) * NFEAT;
#pragma unroll
            for (int w = 0; w < NFEAT; ++w)
                v = fmaf(Kr[w], w_layers[w * DIM2 + col], v);
            out_lut[e] = v;
        }
        float m = valid ? fabsf(v) : 0.f;
#pragma unroll
        for (int off = 32; off >= 1; off >>= 1) m = fmaxf(m, __shfl_down(m, off, 64));
        if (lane == 0) smx[wave] = m;
        __syncthreads();
        if (tid == 0) {
            float bm = 0.f;
#pragma unroll
            for (int w2 = 0; w2 < 16; ++w2) bm = fmaxf(bm, smx[w2]);
            atomicMax(amax, __float_as_uint(bm));   // fabs => sign bit 0, uint order ok
        }
    }
    __threadfence();
    grid.sync();
    __threadfence();

    // ------- Phase D: per-block re-quantize into own LDS, then apply -------
    if (tid == 0) bmax_s = __uint_as_float(atomicAdd(amax, 0u));  // coherent read
    __syncthreads();
    const float bmax = bmax_s;
    {
        // Recompute LUT values from LDS-resident K (bitwise-identical fma chain
        // to phase C) and quantize to BIASED uint8 (q+127 in [0,254]) in LDS.
        float inv = 127.0f / bmax;
        for (int i = tid; i < DIM3; i += 1024) {
            int ii = i / DIM2;
            int jj = (i / DIM) % DIM;
            int kk = i % DIM;
            const float* K0 = K_s + kk * NFEAT;              // c=0: a=k, col=i*DIM+j
            const float* K1 = K_s + (DIM + jj) * NFEAT;      // c=1: a=j, col=i*DIM+k
            const float* K2 = K_s + (2 * DIM + ii) * NFEAT;  // c=2: a=i, col=j*DIM+k
            int col0 = ii * DIM + jj, col1 = ii * DIM + kk, col2 = jj * DIM + kk;
            float v0 = 0.f, v1 = 0.f, v2 = 0.f;
#pragma unroll
            for (int w = 0; w < NFEAT; ++w) {
                v0 = fmaf(K0[w], w_layers[w * DIM2 + col0], v0);
                v1 = fmaf(K1[w], w_layers[w * DIM2 + col1], v1);
                v2 = fmaf(K2[w], w_layers[w * DIM2 + col2], v2);
            }
            int c0 = min(max((int)rintf(v0 * inv), -127), 127) + 127;
            int c1 = min(max((int)rintf(v1 * inv), -127), 127) + 127;
            int c2 = min(max((int)rintf(v2 * inv), -127), 127) + 127;
            qs[i] = (unsigned)c0 | ((unsigned)c1 << 8) | ((unsigned)c2 << 16);
        }
    }
    __syncthreads();

    // ---- trilinear apply: software-pipelined, two-phase LDS issue/consume --
    float scale = bmax * (1.0f / 127.0f);
    constexpr float INV_BIN = 32.0f / 1.000001f;
    const float4* R4 = (const float4*)img;
    const float4* G4 = (const float4*)(img + IMG_HW);
    const float4* B4 = (const float4*)(img + 2 * IMG_HW);

    int t = bid * 1024 + tid;                 // grid = 256 blocks
    const int stride = 256 * 1024;

    float4 rv = R4[t], gv = G4[t], bv = B4[t];
    while (true) {
        int tn = t + stride;
        bool more = tn < NGROUPS;
        float4 rvn, gvn, bvn;
        if (more) { rvn = R4[tn]; gvn = G4[tn]; bvn = B4[tn]; }  // prefetch

        float rr[4] = {rv.x, rv.y, rv.z, rv.w};
        float gg[4] = {gv.x, gv.y, gv.z, gv.w};
        float bb[4] = {bv.x, bv.y, bv.z, bv.w};

        // phase 1: all indices + weights; issue ALL 16 LDS pair-reads
        unsigned int lo[16], hi[16];
        float w2[16], rdv[4];
#pragma unroll
        for (int q = 0; q < 4; ++q) {
            float rf = rr[q] * INV_BIN, gf = gg[q] * INV_BIN, bf = bb[q] * INV_BIN;
            float rfl = floorf(rf), gfl = floorf(gf), bfl = floorf(bf);
            int rid = min(max((int)rfl, 0), DIM - 2);
            int gid = min(max((int)gfl, 0), DIM - 2);
            int bidb = min(max((int)bfl, 0), DIM - 2);
            float rd = rf - rfl, gd = gf - gfl, bd = bf - bfl;
            rdv[q] = rd;
            int base = (bidb * DIM + gid) * DIM + rid;
#pragma unroll
            for (int db = 0; db < 2; ++db) {
                float wb = db ? bd : 1.0f - bd;
#pragma unroll
                for (int dg = 0; dg < 2; ++dg) {
                    int j = q * 4 + db * 2 + dg;
                    w2[j] = wb * (dg ? gd : 1.0f - gd);
                    int idx = base + (db * DIM + dg) * DIM;
                    lo[j] = qs[idx];          // ds_read2_b32, 16 outstanding
                    hi[j] = qs[idx + 1];
                }
            }
        }
        // phase 2: consume. Values biased +127; trilinear weights sum to 1,
        // so subtracting 127 once per channel removes the bias exactly.
        float ro[4], go[4], bo[4];
#pragma unroll
        for (int q = 0; q < 4; ++q) {
            float rd = rdv[q], accR = 0.f, accG = 0.f, accB = 0.f;
#pragma unroll
            for (int jj = 0; jj < 4; ++jj) {
                int j = q * 4 + jj;
                float w0 = w2[j] * (1.0f - rd), w1 = w2[j] * rd;
                accR = fmaf(w0, ub(lo[j], 0), fmaf(w1, ub(hi[j], 0), accR));
                accG = fmaf(w0, ub(lo[j], 1), fmaf(w1, ub(hi[j], 1), accG));
                accB = fmaf(w0, ub(lo[j], 2), fmaf(w1, ub(hi[j], 2), accB));
            }
            ro[q] = fmaf(scale, accR - 127.0f, rr[q]);
            go[q] = fmaf(scale, accG - 127.0f, gg[q]);
            bo[q] = fmaf(scale, accB - 127.0f, bb[q]);
        }
        ((float4*)out)[t]                = make_float4(ro[0], ro[1], ro[2], ro[3]);
        ((float4*)(out + IMG_HW))[t]     = make_float4(go[0], go[1], go[2], go[3]);
        ((float4*)(out + 2 * IMG_HW))[t] = make_float4(bo[0], bo[1], bo[2], bo[3]);

        if (!more) break;
        t = tn; rv = rvn; gv = gvn; bv = bvn;
    }
}

extern "C" void kernel_launch(void* const* d_in, const int* in_sizes, int n_in,
                              void* d_out, int out_size, void* d_ws, size_t ws_size,
                              hipStream_t stream) {
    const int*   img_msb     = (const int*)d_in[0];
    const int*   img_lsb     = (const int*)d_in[1];
    const float* img_org     = (const float*)d_in[2];
    const float* feature_msb = (const float*)d_in[3];
    const float* feature_lsb = (const float*)d_in[4];
    const float* lut_cat     = (const float*)d_in[5];
    const float* s_layers    = (const float*)d_in[6];
    const float* w_layers    = (const float*)d_in[7];
    const float* luts        = (const float*)d_in[8];
    float* out = (float*)d_out;

    unsigned int* wsu     = (unsigned int*)d_ws;
    unsigned int* amax    = wsu;                   // [0]
    float*        partial = (float*)d_ws + 16;     // 640 floats used
    float*        Kg      = (float*)d_ws + 4096;   // 990 floats
    float*        out_lut = out + IMG_ELEMS;

    static const size_t LDS_BYTES = DIM3 * sizeof(unsigned int);  // 143748
    hipFuncSetAttribute((const void*)fused_all,
                        hipFuncAttributeMaxDynamicSharedMemorySize, (int)LDS_BYTES);

    hipMemsetAsync(wsu, 0, 8, stream);   // amax (+spare)

    void* args[] = {
        (void*)&img_msb, (void*)&img_lsb,
        (void*)&feature_msb, (void*)&feature_lsb,
        (void*)&lut_cat, (void*)&s_layers, (void*)&luts, (void*)&w_layers,
        (void*)&img_org,
        (void*)&partial, (void*)&Kg, (void*)&amax,
        (void*)&out_lut, (void*)&out
    };
    hipLaunchCooperativeKernel((const void*)fused_all, dim3(256), dim3(1024),
                               args, (unsigned int)LDS_BYTES, stream);
}

// Round 5
// 242.256 us; speedup vs baseline: 3.1323x; 3.1323x over previous
//
#include <hip/hip_runtime.h>

#define HW_S   65536      // 256*256 small image pixels
#define NFEAT  10
#define DIM    33
#define DIM2   1089       // 33^2
#define DIM3   35937      // 33^3
#define LUT_ELEMS (3*DIM3)
#define IMG_HW 8294400    // 2160*3840
#define IMG_ELEMS (3*IMG_HW)
#define NGROUPS (IMG_HW/4)

// ws layout (32-bit slots): [0]=amax bits, [1]=counter1, [2]=counter2,
// [16..2576)=partials, [4096..5086)=K

// ---------------- Stage 1: gather+pool, last block computes K ---------------
__global__ __launch_bounds__(256) void feat_and_K(
    const int* __restrict__ msb, const int* __restrict__ lsb,
    const float* __restrict__ fm, const float* __restrict__ fl,
    const float* __restrict__ lut_cat, const float* __restrict__ s_layers,
    const float* __restrict__ luts,
    float* __restrict__ partial, unsigned int* __restrict__ counter,
    float* __restrict__ Kout)
{
    int tid = threadIdx.x;
    int p = blockIdx.x * 256 + tid;
    int im = msb[p] * 4096 + msb[HW_S + p] * 256 + msb[2 * HW_S + p] * 16;
    int il = lsb[p] * 4096 + lsb[HW_S + p] * 256 + lsb[2 * HW_S + p] * 16;
    const float2* rm = (const float2*)(fm + im * NFEAT);  // 40B rows: 8B aligned
    const float2* rl = (const float2*)(fl + il * NFEAT);
    float acc[NFEAT];
#pragma unroll
    for (int h = 0; h < 5; ++h) {
        float2 a = rm[h], b = rl[h];
        acc[2 * h]     = a.x + b.x;
        acc[2 * h + 1] = a.y + b.y;
    }
#pragma unroll
    for (int f = 0; f < NFEAT; ++f) {
        float v = acc[f];
#pragma unroll
        for (int off = 32; off >= 1; off >>= 1) v += __shfl_down(v, off, 64);
        acc[f] = v;
    }
    __shared__ float s4[4][NFEAT];
    int lane = tid & 63, wave = tid >> 6;
    if (lane == 0) {
#pragma unroll
        for (int f = 0; f < NFEAT; ++f) s4[wave][f] = acc[f];
    }
    __syncthreads();
    if (tid < NFEAT)
        partial[blockIdx.x * NFEAT + tid] =
            s4[0][tid] + s4[1][tid] + s4[2][tid] + s4[3][tid];

    // ---- last-block finalization (decoupled, device-scope fenced) ----
    __shared__ int lastflag;
    __syncthreads();   // drains the partial[] stores
    if (tid == 0) {
        __threadfence();
        lastflag = (atomicAdd(counter, 1u) == 255u) ? 1 : 0;
    }
    __syncthreads();
    if (!lastflag) return;
    __threadfence();   // acquire before reading other blocks' partials

    __shared__ float chunk_s[80];
    __shared__ float pooled_s[NFEAT], w_s[NFEAT], R_s[150];
    if (tid < 80) {   // fixed-order tree: 8 chunks x 32 blocks, per feature
        int f = tid % 10, ch = tid / 10;
        float s = 0.f;
        for (int b = ch * 32; b < ch * 32 + 32; ++b) s += partial[b * NFEAT + f];
        chunk_s[tid] = s;
    }
    __syncthreads();
    if (tid < NFEAT) {
        float v = 0.f;
#pragma unroll
        for (int ch = 0; ch < 8; ++ch) v += chunk_s[ch * 10 + tid];
        v *= (1.0f / 65536.0f);
        v = rintf(v * 2.0f) * 0.5f;
        v = fminf(fmaxf(v, -16.0f), 15.5f);
        pooled_s[tid] = v;
    }
    __syncthreads();
    if (tid < NFEAT) {
        float wsum = 0.f;
        for (int i = 0; i < 5; ++i) {
            int m0 = (int)(pooled_s[2 * i] * 2.0f) + 32;
            int m1 = (int)(pooled_s[2 * i + 1] * 2.0f) + 32;
            wsum += (lut_cat[(i * 4096 + m0 * 64 + m1) * NFEAT + tid] - 32.0f) * 0.25f;
        }
        w_s[tid] = wsum;
    }
    __syncthreads();
    if (tid < 150) {  // R[s][c][w] = sum_n weights[n] * luts[s*30+n*3+c, w]
        int w = tid % 10, sc = tid / 10, c = sc % 3, s = sc / 3;
        float r = 0.f;
        for (int n = 0; n < NFEAT; ++n)
            r += w_s[n] * luts[(s * 30 + n * 3 + c) * NFEAT + w];
        R_s[tid] = r;
    }
    __syncthreads();
    for (int t = tid; t < 3 * DIM * NFEAT; t += 256) {  // K[c][a][w]
        int w = t % 10, a = (t / 10) % DIM, c = t / (10 * DIM);
        float k = 0.f;
#pragma unroll
        for (int s = 0; s < 5; ++s)
            k += s_layers[a * 5 + s] * R_s[(s * 3 + c) * 10 + w];
        Kout[t] = k;
    }
}

// ---- Stage 2: f32 d3lut + absmax (parallel), last block quantizes ----------
__global__ __launch_bounds__(1024) void lut_and_quant(
    const float* __restrict__ K, const float* __restrict__ w_layers,
    float* __restrict__ out_lut, unsigned int* __restrict__ amax,
    unsigned int* __restrict__ counter2, unsigned int* __restrict__ q)
{
    int tid = threadIdx.x;
    int e = blockIdx.x * 1024 + tid;
    float v = 0.f;
    bool valid = e < LUT_ELEMS;
    if (valid) {
        int c = e / DIM3;
        int rem = e - c * DIM3;
        int i = rem / DIM2;
        int j = (rem / DIM) % DIM;
        int k = rem % DIM;
        int a, col;
        if (c == 0)      { a = k; col = i * DIM + j; }
        else if (c == 1) { a = j; col = i * DIM + k; }
        else             { a = i; col = j * DIM + k; }
        const float* Kr = K + (c * DIM + a) * NFEAT;
#pragma unroll
        for (int w = 0; w < NFEAT; ++w)
            v = fmaf(Kr[w], w_layers[w * DIM2 + col], v);
        out_lut[e] = v;
    }
    float m = valid ? fabsf(v) : 0.f;
#pragma unroll
    for (int off = 32; off >= 1; off >>= 1) m = fmaxf(m, __shfl_down(m, off, 64));
    __shared__ float smx[16];
    int lane = tid & 63, wave = tid >> 6;
    if (lane == 0) smx[wave] = m;
    __syncthreads();
    if (tid == 0) {
        float bm = 0.f;
#pragma unroll
        for (int w2 = 0; w2 < 16; ++w2) bm = fmaxf(bm, smx[w2]);
        atomicMax(amax, __float_as_uint(bm));   // fabs => sign bit 0, uint order ok
    }

    // ---- last-block election: quantize to BIASED uint8 (q+127 in [0,254]) --
    __shared__ int lastflag;
    __syncthreads();   // out_lut stores + amax atomic issued
    if (tid == 0) {
        __threadfence();
        lastflag = (atomicAdd(counter2, 1u) == (unsigned)(gridDim.x - 1)) ? 1 : 0;
    }
    __syncthreads();
    if (!lastflag) return;
    __threadfence();   // acquire: all out_lut + amax visible

    float inv = 127.0f / __uint_as_float(*amax);
    for (int i = tid; i < DIM3; i += 1024) {    // 36 iters; out_lut is L2/L3-hot
        int c0 = min(max((int)rintf(out_lut[i] * inv), -127), 127) + 127;
        int c1 = min(max((int)rintf(out_lut[DIM3 + i] * inv), -127), 127) + 127;
        int c2 = min(max((int)rintf(out_lut[2 * DIM3 + i] * inv), -127), 127) + 127;
        q[i] = (unsigned)c0 | ((unsigned)c1 << 8) | ((unsigned)c2 << 16);
    }
}

// ---------------- Stage 3: trilinear apply, pipelined + two-phase LDS -------
__device__ __forceinline__ float ub(unsigned int w, int b) {
    return (float)((w >> (8 * b)) & 0xffu);   // v_cvt_f32_ubyteN, 1 VALU
}

__global__ __launch_bounds__(1024) void apply_lut(
    const float* __restrict__ img, const unsigned int* __restrict__ qtab,
    const unsigned int* __restrict__ amax, float* __restrict__ out)
{
    extern __shared__ unsigned int qs[];   // 35937 dwords = 143748 B
    for (int i = threadIdx.x; i < 8984; i += 1024)
        ((uint4*)qs)[i] = ((const uint4*)qtab)[i];
    if (threadIdx.x == 0) qs[35936] = qtab[35936];
    __syncthreads();

    float scale = __uint_as_float(*amax) * (1.0f / 127.0f);
    constexpr float INV_BIN = 32.0f / 1.000001f;
    const float4* R4 = (const float4*)img;
    const float4* G4 = (const float4*)(img + IMG_HW);
    const float4* B4 = (const float4*)(img + 2 * IMG_HW);

    int t = blockIdx.x * 1024 + threadIdx.x;     // grid = 256 blocks
    const int stride = gridDim.x * 1024;

    // software pipeline: current tile in (rv,gv,bv), next tile prefetched
    float4 rv = R4[t], gv = G4[t], bv = B4[t];
    while (true) {
        int tn = t + stride;
        bool more = tn < NGROUPS;
        float4 rvn, gvn, bvn;
        if (more) { rvn = R4[tn]; gvn = G4[tn]; bvn = B4[tn]; }

        float rr[4] = {rv.x, rv.y, rv.z, rv.w};
        float gg[4] = {gv.x, gv.y, gv.z, gv.w};
        float bb[4] = {bv.x, bv.y, bv.z, bv.w};

        // phase 1: all indices + weights; issue ALL 16 LDS pair-reads
        unsigned int lo[16], hi[16];
        float w2[16], rdv[4];
#pragma unroll
        for (int q = 0; q < 4; ++q) {
            float rf = rr[q] * INV_BIN, gf = gg[q] * INV_BIN, bf = bb[q] * INV_BIN;
            float rfl = floorf(rf), gfl = floorf(gf), bfl = floorf(bf);
            int rid = min(max((int)rfl, 0), DIM - 2);
            int gid = min(max((int)gfl, 0), DIM - 2);
            int bid = min(max((int)bfl, 0), DIM - 2);
            float rd = rf - rfl, gd = gf - gfl, bd = bf - bfl;
            rdv[q] = rd;
            int base = (bid * DIM + gid) * DIM + rid;
#pragma unroll
            for (int db = 0; db < 2; ++db) {
                float wb = db ? bd : 1.0f - bd;
#pragma unroll
                for (int dg = 0; dg < 2; ++dg) {
                    int j = q * 4 + db * 2 + dg;
                    w2[j] = wb * (dg ? gd : 1.0f - gd);
                    int idx = base + (db * DIM + dg) * DIM;
                    lo[j] = qs[idx];          // ds_read2_b32, 16 outstanding
                    hi[j] = qs[idx + 1];
                }
            }
        }
        // phase 2: consume. Values biased +127; trilinear weights sum to 1,
        // so subtracting 127 once per channel removes the bias exactly.
        float ro[4], go[4], bo[4];
#pragma unroll
        for (int q = 0; q < 4; ++q) {
            float rd = rdv[q], accR = 0.f, accG = 0.f, accB = 0.f;
#pragma unroll
            for (int jj = 0; jj < 4; ++jj) {
                int j = q * 4 + jj;
                float w0 = w2[j] * (1.0f - rd), w1 = w2[j] * rd;
                accR = fmaf(w0, ub(lo[j], 0), fmaf(w1, ub(hi[j], 0), accR));
                accG = fmaf(w0, ub(lo[j], 1), fmaf(w1, ub(hi[j], 1), accG));
                accB = fmaf(w0, ub(lo[j], 2), fmaf(w1, ub(hi[j], 2), accB));
            }
            ro[q] = fmaf(scale, accR - 127.0f, rr[q]);
            go[q] = fmaf(scale, accG - 127.0f, gg[q]);
            bo[q] = fmaf(scale, accB - 127.0f, bb[q]);
        }
        ((float4*)out)[t]                = make_float4(ro[0], ro[1], ro[2], ro[3]);
        ((float4*)(out + IMG_HW))[t]     = make_float4(go[0], go[1], go[2], go[3]);
        ((float4*)(out + 2 * IMG_HW))[t] = make_float4(bo[0], bo[1], bo[2], bo[3]);

        if (!more) break;
        t = tn; rv = rvn; gv = gvn; bv = bvn;
    }
}

extern "C" void kernel_launch(void* const* d_in, const int* in_sizes, int n_in,
                              void* d_out, int out_size, void* d_ws, size_t ws_size,
                              hipStream_t stream) {
    const int*   img_msb     = (const int*)d_in[0];
    const int*   img_lsb     = (const int*)d_in[1];
    const float* img_org     = (const float*)d_in[2];
    const float* feature_msb = (const float*)d_in[3];
    const float* feature_lsb = (const float*)d_in[4];
    const float* lut_cat     = (const float*)d_in[5];
    const float* s_layers    = (const float*)d_in[6];
    const float* w_layers    = (const float*)d_in[7];
    const float* luts        = (const float*)d_in[8];
    float* out = (float*)d_out;

    unsigned int* wsu      = (unsigned int*)d_ws;
    unsigned int* amax     = wsu;                   // [0]
    unsigned int* counter1 = wsu + 1;               // [1]
    unsigned int* counter2 = wsu + 2;               // [2]
    float*        partial  = (float*)d_ws + 16;     // 2560 floats
    float*        K        = (float*)d_ws + 4096;   // 990 floats
    unsigned int* q        = wsu + 8448;            // 35937 dwords, 16B aligned
    float*        out_lut  = out + IMG_ELEMS;

    static const size_t LDS_BYTES = DIM3 * sizeof(unsigned int);  // 143748
    hipFuncSetAttribute((const void*)apply_lut,
                        hipFuncAttributeMaxDynamicSharedMemorySize, (int)LDS_BYTES);

    hipMemsetAsync(wsu, 0, 16, stream);   // amax + counters
    feat_and_K<<<256, 256, 0, stream>>>(img_msb, img_lsb, feature_msb, feature_lsb,
                                        lut_cat, s_layers, luts, partial, counter1, K);
    lut_and_quant<<<(LUT_ELEMS + 1023) / 1024, 1024, 0, stream>>>(
        K, w_layers, out_lut, amax, counter2, q);
    apply_lut<<<256, 1024, LDS_BYTES, stream>>>(img_org, q, amax, out);
}

// Round 6
// 229.774 us; speedup vs baseline: 3.3025x; 1.0543x over previous
//
#include <hip/hip_runtime.h>

#define HW_S   65536      // 256*256 small image pixels
#define NFEAT  10
#define DIM    33
#define DIM3   35937      // 33^3
#define LUT_ELEMS (3*DIM3)
#define IMG_HW 8294400    // 2160*3840
#define IMG_ELEMS (3*IMG_HW)
#define NGROUPS (IMG_HW/4)

typedef float f32x4 __attribute__((ext_vector_type(4)));

// ws layout (32-bit slots): [0]=amax bits, [1]=counter, [16..2576)=partials,
// [4096..5086)=K, [8448..44385)=quantized LUT dwords

// ---------------- Stage 1: gather+pool, last block computes K ---------------
__global__ __launch_bounds__(256) void feat_and_K(
    const int* __restrict__ msb, const int* __restrict__ lsb,
    const float* __restrict__ fm, const float* __restrict__ fl,
    const float* __restrict__ lut_cat, const float* __restrict__ s_layers,
    const float* __restrict__ luts,
    float* __restrict__ partial, unsigned int* __restrict__ counter,
    float* __restrict__ Kout)
{
    int tid = threadIdx.x;
    int p = blockIdx.x * 256 + tid;
    int im = msb[p] * 4096 + msb[HW_S + p] * 256 + msb[2 * HW_S + p] * 16;
    int il = lsb[p] * 4096 + lsb[HW_S + p] * 256 + lsb[2 * HW_S + p] * 16;
    const float2* rm = (const float2*)(fm + im * NFEAT);  // 40B rows: 8B aligned
    const float2* rl = (const float2*)(fl + il * NFEAT);
    float acc[NFEAT];
#pragma unroll
    for (int h = 0; h < 5; ++h) {
        float2 a = rm[h], b = rl[h];
        acc[2 * h]     = a.x + b.x;
        acc[2 * h + 1] = a.y + b.y;
    }
#pragma unroll
    for (int f = 0; f < NFEAT; ++f) {
        float v = acc[f];
#pragma unroll
        for (int off = 32; off >= 1; off >>= 1) v += __shfl_down(v, off, 64);
        acc[f] = v;
    }
    __shared__ float s4[4][NFEAT];
    int lane = tid & 63, wave = tid >> 6;
    if (lane == 0) {
#pragma unroll
        for (int f = 0; f < NFEAT; ++f) s4[wave][f] = acc[f];
    }
    __syncthreads();
    if (tid < NFEAT)
        partial[blockIdx.x * NFEAT + tid] =
            s4[0][tid] + s4[1][tid] + s4[2][tid] + s4[3][tid];

    // ---- last-block finalization (decoupled, device-scope fenced) ----
    __shared__ int lastflag;
    __syncthreads();   // drains the partial[] stores
    if (tid == 0) {
        __threadfence();
        lastflag = (atomicAdd(counter, 1u) == 255u) ? 1 : 0;
    }
    __syncthreads();
    if (!lastflag) return;
    __threadfence();   // acquire before reading other blocks' partials

    __shared__ float chunk_s[80];
    __shared__ float pooled_s[NFEAT], w_s[NFEAT], R_s[150];
    if (tid < 80) {   // fixed-order tree: 8 chunks x 32 blocks, per feature
        int f = tid % 10, ch = tid / 10;
        float s = 0.f;
        for (int b = ch * 32; b < ch * 32 + 32; ++b) s += partial[b * NFEAT + f];
        chunk_s[tid] = s;
    }
    __syncthreads();
    if (tid < NFEAT) {
        float v = 0.f;
#pragma unroll
        for (int ch = 0; ch < 8; ++ch) v += chunk_s[ch * 10 + tid];
        v *= (1.0f / 65536.0f);
        v = rintf(v * 2.0f) * 0.5f;
        v = fminf(fmaxf(v, -16.0f), 15.5f);
        pooled_s[tid] = v;
    }
    __syncthreads();
    if (tid < NFEAT) {
        float wsum = 0.f;
        for (int i = 0; i < 5; ++i) {
            int m0 = (int)(pooled_s[2 * i] * 2.0f) + 32;
            int m1 = (int)(pooled_s[2 * i + 1] * 2.0f) + 32;
            wsum += (lut_cat[(i * 4096 + m0 * 64 + m1) * NFEAT + tid] - 32.0f) * 0.25f;
        }
        w_s[tid] = wsum;
    }
    __syncthreads();
    if (tid < 150) {  // R[s][c][w] = sum_n weights[n] * luts[s*30+n*3+c, w]
        int w = tid % 10, sc = tid / 10, c = sc % 3, s = sc / 3;
        float r = 0.f;
        for (int n = 0; n < NFEAT; ++n)
            r += w_s[n] * luts[(s * 30 + n * 3 + c) * NFEAT + w];
        R_s[tid] = r;
    }
    __syncthreads();
    for (int t = tid; t < 3 * DIM * NFEAT; t += 256) {  // K[c][a][w]
        int w = t % 10, a = (t / 10) % DIM, c = t / (10 * DIM);
        float k = 0.f;
#pragma unroll
        for (int s = 0; s < 5; ++s)
            k += s_layers[a * 5 + s] * R_s[(s * 3 + c) * 10 + w];
        Kout[t] = k;
    }
}

// ---------------- Stage 2: materialize d3lut (f32) + global absmax ----------
__global__ __launch_bounds__(256) void compute_lut(
    const float* __restrict__ K, const float* __restrict__ w_layers,
    float* __restrict__ out_lut, unsigned int* __restrict__ amax)
{
    int e = blockIdx.x * 256 + threadIdx.x;
    float v = 0.f;
    bool valid = e < LUT_ELEMS;
    if (valid) {
        int c = e / DIM3;
        int rem = e - c * DIM3;
        int i = rem / (DIM * DIM);
        int j = (rem / DIM) % DIM;
        int k = rem % DIM;
        int a, col;
        if (c == 0)      { a = k; col = i * DIM + j; }
        else if (c == 1) { a = j; col = i * DIM + k; }
        else             { a = i; col = j * DIM + k; }
        const float* Kr = K + (c * DIM + a) * NFEAT;
#pragma unroll
        for (int w = 0; w < NFEAT; ++w) v = fmaf(Kr[w], w_layers[w * 1089 + col], v);
        out_lut[e] = v;
    }
    float m = valid ? fabsf(v) : 0.f;
#pragma unroll
    for (int off = 32; off >= 1; off >>= 1) m = fmaxf(m, __shfl_down(m, off, 64));
    __shared__ float sm[4];
    int lane = threadIdx.x & 63, wave = threadIdx.x >> 6;
    if (lane == 0) sm[wave] = m;
    __syncthreads();
    if (threadIdx.x == 0) {
        float bm = fmaxf(fmaxf(sm[0], sm[1]), fmaxf(sm[2], sm[3]));
        atomicMax(amax, __float_as_uint(bm));
    }
}

// ---------------- Stage 3: pack LUT to interleaved BIASED uint8 -------------
// store q+127 in [0,254] so apply can unpack with v_cvt_f32_ubyteN (1 VALU/byte)
__global__ __launch_bounds__(256) void quantize_lut(
    const float* __restrict__ lut, const unsigned int* __restrict__ amax,
    unsigned int* __restrict__ q)
{
    int i = blockIdx.x * 256 + threadIdx.x;
    if (i >= DIM3) return;
    float inv = 127.0f / __uint_as_float(*amax);
    int c0 = min(max((int)rintf(lut[i] * inv), -127), 127) + 127;
    int c1 = min(max((int)rintf(lut[DIM3 + i] * inv), -127), 127) + 127;
    int c2 = min(max((int)rintf(lut[2 * DIM3 + i] * inv), -127), 127) + 127;
    q[i] = (unsigned)c0 | ((unsigned)c1 << 8) | ((unsigned)c2 << 16);
}

// ---------------- Stage 4: trilinear apply, pipelined + two-phase LDS -------
__device__ __forceinline__ float ub(unsigned int w, int b) {
    return (float)((w >> (8 * b)) & 0xffu);   // v_cvt_f32_ubyteN, 1 VALU
}

__global__ __launch_bounds__(1024) void apply_lut(
    const float* __restrict__ img, const unsigned int* __restrict__ qtab,
    const unsigned int* __restrict__ amax, float* __restrict__ out)
{
    extern __shared__ unsigned int qs[];   // 35937 dwords = 143748 B
    for (int i = threadIdx.x; i < 8984; i += 1024)
        ((uint4*)qs)[i] = ((const uint4*)qtab)[i];
    if (threadIdx.x == 0) qs[35936] = qtab[35936];
    __syncthreads();

    float scale = __uint_as_float(*amax) * (1.0f / 127.0f);
    constexpr float INV_BIN = 32.0f / 1.000001f;
    const float4* R4 = (const float4*)img;
    const float4* G4 = (const float4*)(img + IMG_HW);
    const float4* B4 = (const float4*)(img + 2 * IMG_HW);

    int t = blockIdx.x * 1024 + threadIdx.x;     // grid = 256 blocks
    const int stride = gridDim.x * 1024;

    // software pipeline: current tile in (rv,gv,bv), next tile prefetched
    float4 rv = R4[t], gv = G4[t], bv = B4[t];
    while (true) {
        int tn = t + stride;
        bool more = tn < NGROUPS;
        float4 rvn, gvn, bvn;
        if (more) { rvn = R4[tn]; gvn = G4[tn]; bvn = B4[tn]; }

        float rr[4] = {rv.x, rv.y, rv.z, rv.w};
        float gg[4] = {gv.x, gv.y, gv.z, gv.w};
        float bb[4] = {bv.x, bv.y, bv.z, bv.w};

        // phase 1: all indices + weights; issue ALL 16 LDS pair-reads
        unsigned int lo[16], hi[16];
        float w2[16], rdv[4];
#pragma unroll
        for (int q = 0; q < 4; ++q) {
            float rf = rr[q] * INV_BIN, gf = gg[q] * INV_BIN, bf = bb[q] * INV_BIN;
            float rfl = floorf(rf), gfl = floorf(gf), bfl = floorf(bf);
            int rid = min(max((int)rfl, 0), DIM - 2);
            int gid = min(max((int)gfl, 0), DIM - 2);
            int bid = min(max((int)bfl, 0), DIM - 2);
            float rd = rf - rfl, gd = gf - gfl, bd = bf - bfl;
            rdv[q] = rd;
            int base = (bid * DIM + gid) * DIM + rid;
#pragma unroll
            for (int db = 0; db < 2; ++db) {
                float wb = db ? bd : 1.0f - bd;
#pragma unroll
                for (int dg = 0; dg < 2; ++dg) {
                    int j = q * 4 + db * 2 + dg;
                    w2[j] = wb * (dg ? gd : 1.0f - gd);
                    int idx = base + (db * DIM + dg) * DIM;
                    lo[j] = qs[idx];          // ds_read2_b32, 16 outstanding
                    hi[j] = qs[idx + 1];
                }
            }
        }
        // phase 2: consume. Values biased +127; trilinear weights sum to 1,
        // so subtracting 127 once per channel removes the bias exactly.
        float ro[4], go[4], bo[4];
#pragma unroll
        for (int q = 0; q < 4; ++q) {
            float rd = rdv[q], accR = 0.f, accG = 0.f, accB = 0.f;
#pragma unroll
            for (int jj = 0; jj < 4; ++jj) {
                int j = q * 4 + jj;
                float w0 = w2[j] * (1.0f - rd), w1 = w2[j] * rd;
                accR = fmaf(w0, ub(lo[j], 0), fmaf(w1, ub(hi[j], 0), accR));
                accG = fmaf(w0, ub(lo[j], 1), fmaf(w1, ub(hi[j], 1), accG));
                accB = fmaf(w0, ub(lo[j], 2), fmaf(w1, ub(hi[j], 2), accB));
            }
            ro[q] = fmaf(scale, accR - 127.0f, rr[q]);
            go[q] = fmaf(scale, accG - 127.0f, gg[q]);
            bo[q] = fmaf(scale, accB - 127.0f, bb[q]);
        }
        // streamed output, never re-read: bypass cache with nontemporal stores
        f32x4 rv4 = {ro[0], ro[1], ro[2], ro[3]};
        f32x4 gv4 = {go[0], go[1], go[2], go[3]};
        f32x4 bv4 = {bo[0], bo[1], bo[2], bo[3]};
        __builtin_nontemporal_store(rv4, (f32x4*)out + t);
        __builtin_nontemporal_store(gv4, (f32x4*)(out + IMG_HW) + t);
        __builtin_nontemporal_store(bv4, (f32x4*)(out + 2 * IMG_HW) + t);

        if (!more) break;
        t = tn; rv = rvn; gv = gvn; bv = bvn;
    }
}

extern "C" void kernel_launch(void* const* d_in, const int* in_sizes, int n_in,
                              void* d_out, int out_size, void* d_ws, size_t ws_size,
                              hipStream_t stream) {
    const int*   img_msb     = (const int*)d_in[0];
    const int*   img_lsb     = (const int*)d_in[1];
    const float* img_org     = (const float*)d_in[2];
    const float* feature_msb = (const float*)d_in[3];
    const float* feature_lsb = (const float*)d_in[4];
    const float* lut_cat     = (const float*)d_in[5];
    const float* s_layers    = (const float*)d_in[6];
    const float* w_layers    = (const float*)d_in[7];
    const float* luts        = (const float*)d_in[8];
    float* out = (float*)d_out;

    unsigned int* wsu     = (unsigned int*)d_ws;
    unsigned int* amax    = wsu;                   // [0]
    unsigned int* counter = wsu + 1;               // [1]
    float*        partial = (float*)d_ws + 16;     // 2560 floats
    float*        K       = (float*)d_ws + 4096;   // 990 floats
    unsigned int* q       = wsu + 8448;            // 35937 dwords, 16B aligned

    static const size_t LDS_BYTES = DIM3 * sizeof(unsigned int);  // 143748
    hipFuncSetAttribute((const void*)apply_lut,
                        hipFuncAttributeMaxDynamicSharedMemorySize, (int)LDS_BYTES);

    hipMemsetAsync(wsu, 0, 8, stream);   // amax + counter
    feat_and_K<<<256, 256, 0, stream>>>(img_msb, img_lsb, feature_msb, feature_lsb,
                                        lut_cat, s_layers, luts, partial, counter, K);
    compute_lut<<<(LUT_ELEMS + 255) / 256, 256, 0, stream>>>(K, w_layers,
                                                             out + IMG_ELEMS, amax);
    quantize_lut<<<(DIM3 + 255) / 256, 256, 0, stream>>>(out + IMG_ELEMS, amax, q);
    apply_lut<<<256, 1024, LDS_BYTES, stream>>>(img_org, q, amax, out);
}